// Round 1
// baseline (1654.030 us; speedup 1.0000x reference)
//
#include <hip/hip_runtime.h>
#include <hip/hip_bf16.h>

typedef __attribute__((ext_vector_type(4))) float f32x4;
typedef __attribute__((ext_vector_type(8))) __bf16 bf16x8;
typedef unsigned short u16;

// ---------- helpers ----------
__device__ __forceinline__ u16 f2bf(float f) {
  __bf16 h = (__bf16)f;                 // compiler emits RNE cvt (pairs into v_cvt_pk_bf16_f32)
  return __builtin_bit_cast(u16, h);
}
__device__ __forceinline__ float bf2f(u16 b) {
  return __uint_as_float(((unsigned)b) << 16);
}

__device__ __forceinline__ bf16x8 load_frag(const float* p) {
  f32x4 a = *(const f32x4*)p;
  f32x4 b = *(const f32x4*)(p + 4);
  bf16x8 r;
  r[0] = (__bf16)a[0]; r[1] = (__bf16)a[1]; r[2] = (__bf16)a[2]; r[3] = (__bf16)a[3];
  r[4] = (__bf16)b[0]; r[5] = (__bf16)b[1]; r[6] = (__bf16)b[2]; r[7] = (__bf16)b[3];
  return r;
}
__device__ __forceinline__ bf16x8 load_frag(const u16* p) {
  return *(const bf16x8*)p;            // raw bf16 bits, 16B aligned
}

// ---------- generic GEMM: C[256 x N] (+)= A[256 x K] @ B[N x K]^T ----------
// grid.x = N/32, grid.y = K-splits (klen each), grid.z = batch
// A row stride = K, B row stride = K. CMODE: 0 = store f32, 1 = store bf16, 2 = atomicAdd f32
template<typename TA, typename TB, int CMODE>
__global__ __launch_bounds__(256) void gemm256(
    const TA* __restrict__ A, const TB* __restrict__ B, void* __restrict__ Cv,
    int K, int klen, long long a_zs, long long b_zs, long long c_zs,
    int ldc, int bzdiv)
{
  int z = blockIdx.z;
  A += (long long)z * a_zs;
  B += (long long)(z / bzdiv) * b_zs;
  int n0 = blockIdx.x * 32;
  int kb = blockIdx.y * klen;
  int tid = threadIdx.x;
  int lane = tid & 63;
  int w = tid >> 6;                    // wave: rows [w*64, w*64+64)
  int r0 = lane & 15;
  int kof = (lane >> 4) << 3;          // lane-group k offset (0,8,16,24)

  f32x4 acc[4][2];
#pragma unroll
  for (int i = 0; i < 4; i++)
#pragma unroll
    for (int j = 0; j < 2; j++) acc[i][j] = (f32x4){0.f, 0.f, 0.f, 0.f};

  const TA* a0 = A + (long long)(w * 64 + r0) * K + kof;
  const TB* b0 = B + (long long)(n0 + r0) * K + kof;

  for (int k = kb; k < kb + klen; k += 32) {
    bf16x8 af[4], bfr[2];
#pragma unroll
    for (int i = 0; i < 4; i++) af[i] = load_frag(a0 + (long long)i * 16 * K + k);
#pragma unroll
    for (int j = 0; j < 2; j++) bfr[j] = load_frag(b0 + (long long)j * 16 * K + k);
#pragma unroll
    for (int i = 0; i < 4; i++)
#pragma unroll
      for (int j = 0; j < 2; j++)
        acc[i][j] = __builtin_amdgcn_mfma_f32_16x16x32_bf16(af[i], bfr[j], acc[i][j], 0, 0, 0);
  }

  int rr = (lane >> 4) * 4;
  int cbase = n0 + (lane & 15);
#pragma unroll
  for (int i = 0; i < 4; i++)
#pragma unroll
    for (int j = 0; j < 2; j++)
#pragma unroll
      for (int q = 0; q < 4; q++) {
        int row = w * 64 + i * 16 + rr + q;
        int col = cbase + j * 16;
        long long cidx = (long long)row * ldc + col + (long long)z * c_zs;
        float v = acc[i][j][q];
        if (CMODE == 0)      ((float*)Cv)[cidx] = v;
        else if (CMODE == 1) ((u16*)Cv)[cidx] = f2bf(v);
        else                 atomicAdd(((float*)Cv) + cidx, v);
      }
}

// ---------- rmsnorm (sum variant, no eps, no weight): x = h * rsqrt(sum h^2) ----------
__global__ __launch_bounds__(256) void rmsnorm_k(const float* __restrict__ h, float* __restrict__ x) {
  int s = blockIdx.x, tid = threadIdx.x;
  __shared__ float red[4];
  f32x4 hv = ((const f32x4*)(h + s * 1024))[tid];
  float ss = hv[0]*hv[0] + hv[1]*hv[1] + hv[2]*hv[2] + hv[3]*hv[3];
#pragma unroll
  for (int off = 32; off > 0; off >>= 1) ss += __shfl_xor(ss, off, 64);
  int lane = tid & 63, w = tid >> 6;
  if (lane == 0) red[w] = ss;
  __syncthreads();
  ss = red[0] + red[1] + red[2] + red[3];
  float r = 1.0f / sqrtf(ss);
  f32x4 o; o[0]=hv[0]*r; o[1]=hv[1]*r; o[2]=hv[2]*r; o[3]=hv[3]*r;
  ((f32x4*)(x + s * 1024))[tid] = o;
}

// ---------- final norm: out = h * rsqrt(mean h^2 + 1e-6) * w ----------
__global__ __launch_bounds__(256) void final_norm(const float* __restrict__ h,
                                                  const float* __restrict__ nw,
                                                  float* __restrict__ out) {
  int s = blockIdx.x, tid = threadIdx.x;
  __shared__ float red[4];
  f32x4 hv = ((const f32x4*)(h + s * 1024))[tid];
  float ss = hv[0]*hv[0] + hv[1]*hv[1] + hv[2]*hv[2] + hv[3]*hv[3];
#pragma unroll
  for (int off = 32; off > 0; off >>= 1) ss += __shfl_xor(ss, off, 64);
  int lane = tid & 63, w = tid >> 6;
  if (lane == 0) red[w] = ss;
  __syncthreads();
  ss = red[0] + red[1] + red[2] + red[3];
  float r = 1.0f / sqrtf(ss * (1.0f / 1024.0f) + 1e-6f);
  f32x4 wv = ((const f32x4*)nw)[tid];
  f32x4 o; o[0]=hv[0]*r*wv[0]; o[1]=hv[1]*r*wv[1]; o[2]=hv[2]*r*wv[2]; o[3]=hv[3]*r*wv[3];
  ((f32x4*)(out + s * 1024))[tid] = o;
}

// ---------- transpose past K/V into bf16 MFMA-friendly layouts ----------
// Kb[kvh][t][d] (t rows, d contig)  <- pk[kvh][d][t]
// Vb[kvh][d][t] (d rows, t contig)  <- pv[kvh][t][d]
__global__ __launch_bounds__(256) void transpose_past(const float* __restrict__ pk,
                                                      const float* __restrict__ pv,
                                                      u16* __restrict__ Kb, u16* __restrict__ Vb) {
  __shared__ float tile[64][65];
  int t0 = blockIdx.x * 64;
  int kvh = blockIdx.y;
  int tid = threadIdx.x;
  if (blockIdx.z == 0) {
    const float* src = pk + kvh * 64 * 2048;       // [d][t]
#pragma unroll
    for (int r = 0; r < 16; r++) {
      int idx = r * 256 + tid; int d = idx >> 6, t = idx & 63;
      tile[d][t] = src[d * 2048 + t0 + t];
    }
    __syncthreads();
    u16* dst = Kb + kvh * 2304 * 64;               // [t][d]
#pragma unroll
    for (int r = 0; r < 16; r++) {
      int idx = r * 256 + tid; int t = idx >> 6, d = idx & 63;
      dst[(t0 + t) * 64 + d] = f2bf(tile[d][t]);
    }
  } else {
    const float* src = pv + kvh * 2048 * 64;       // [t][d]
#pragma unroll
    for (int r = 0; r < 16; r++) {
      int idx = r * 256 + tid; int t = idx >> 6, d = idx & 63;
      tile[t][d] = src[(t0 + t) * 64 + d];
    }
    __syncthreads();
    u16* dst = Vb + kvh * 64 * 2304;               // [d][t]
#pragma unroll
    for (int r = 0; r < 16; r++) {
      int idx = r * 256 + tid; int d = idx >> 6, t = idx & 63;
      dst[d * 2304 + t0 + t] = f2bf(tile[t][d]);
    }
  }
}

// ---------- rope on q/k (no negation variant!), scatter to qb / Kb / Vb ----------
// out[d] = x[d]*cos[d] + x[(d+32)%64]*sin[d] for heads 0..17; v (heads 18,19) copied.
__global__ __launch_bounds__(256) void rope_scatter(const float* __restrict__ qkv,
                                                    const float* __restrict__ cs,
                                                    const float* __restrict__ sn,
                                                    u16* __restrict__ qb,
                                                    u16* __restrict__ Kb,
                                                    u16* __restrict__ Vb) {
  int s = blockIdx.x, tid = threadIdx.x;
  const float* row = qkv + s * 1280;
  for (int i = tid; i < 1280; i += 256) {
    int hh = i >> 6, d = i & 63;
    float v = row[i];
    if (hh < 18) {
      float vr = row[(hh << 6) | ((d + 32) & 63)];
      v = v * cs[s * 64 + d] + vr * sn[s * 64 + d];
      if (hh < 16) qb[hh * (256 * 64) + s * 64 + d] = f2bf(v);
      else         Kb[(hh - 16) * (2304 * 64) + (2048 + s) * 64 + d] = f2bf(v);
    } else {
      Vb[(hh - 18) * (64 * 2304) + d * 2304 + 2048 + s] = f2bf(v);
    }
  }
}

// ---------- row softmax in place on bf16 scores, causal: valid t in [0, 2049+s) ----------
__global__ __launch_bounds__(256) void softmax_rows(u16* __restrict__ S) {
  int bid = blockIdx.x;                // hh*256 + s
  int s = bid & 255;
  int valid = 2049 + s;
  u16* row = S + (long long)bid * 2304;
  int tid = threadIdx.x;
  __shared__ float red[4];
  float v[9];
  float m = -1e30f;
#pragma unroll
  for (int i = 0; i < 9; i++) {
    int t = tid + i * 256;
    float xv = bf2f(row[t]);
    v[i] = (t < valid) ? xv : -1e30f;
    m = fmaxf(m, v[i]);
  }
#pragma unroll
  for (int off = 32; off > 0; off >>= 1) m = fmaxf(m, __shfl_xor(m, off, 64));
  int lane = tid & 63, w = tid >> 6;
  if (lane == 0) red[w] = m;
  __syncthreads();
  m = fmaxf(fmaxf(red[0], red[1]), fmaxf(red[2], red[3]));
  __syncthreads();
  float ssum = 0.f;
#pragma unroll
  for (int i = 0; i < 9; i++) {
    float e = __expf(v[i] - m);        // -1e30 -> 0
    v[i] = e;
    ssum += e;
  }
#pragma unroll
  for (int off = 32; off > 0; off >>= 1) ssum += __shfl_xor(ssum, off, 64);
  if (lane == 0) red[w] = ssum;
  __syncthreads();
  ssum = red[0] + red[1] + red[2] + red[3];
  float inv = 1.0f / ssum;
#pragma unroll
  for (int i = 0; i < 9; i++) row[tid + i * 256] = f2bf(v[i] * inv);
}

// ---------- silu(gate) * up ----------
__global__ __launch_bounds__(256) void silu_mul(const float* __restrict__ gu, float* __restrict__ y) {
  int t = blockIdx.x * 256 + threadIdx.x;   // f32x4 index, 262144 total
  int s = t >> 10, f4 = t & 1023;
  f32x4 g = ((const f32x4*)gu)[s * 2048 + f4];
  f32x4 u = ((const f32x4*)gu)[s * 2048 + 1024 + f4];
  f32x4 o;
#pragma unroll
  for (int c = 0; c < 4; c++) {
    float gg = g[c];
    o[c] = (gg / (1.0f + __expf(-gg))) * u[c];
  }
  ((f32x4*)y)[t] = o;
}

// ---------- launch ----------
extern "C" void kernel_launch(void* const* d_in, const int* in_sizes, int n_in,
                              void* d_out, int out_size, void* d_ws, size_t ws_size,
                              hipStream_t stream) {
  (void)in_sizes; (void)n_in; (void)out_size; (void)ws_size;
  const float* hs   = (const float*)d_in[0];
  const float* rc   = (const float*)d_in[1];
  const float* rs   = (const float*)d_in[2];
  // d_in[3] attention_mask: computed analytically
  const float* pk   = (const float*)d_in[4];
  const float* pv   = (const float*)d_in[5];
  const float* qkvw = (const float*)d_in[6];
  const float* ow   = (const float*)d_in[7];
  const float* guw  = (const float*)d_in[8];
  const float* dw   = (const float*)d_in[9];
  const float* nw   = (const float*)d_in[10];
  float* out = (float*)d_out;

  char* base = (char*)d_ws;              // ~36 MB used
  float* h    = (float*)(base);                    // 1 MB
  float* x    = (float*)(base + 1048576);          // 1 MB
  float* qkv  = (float*)(base + 2097152);          // 1.25 MB
  float* gu   = (float*)(base + 3407872);          // 8 MB
  float* y    = (float*)(base + 11796480);         // 4 MB
  float* oacc = (float*)(base + 15990784);         // 1 MB
  u16*   qb   = (u16*)(base + 17039360);           // 0.5 MB
  u16*   Kb   = (u16*)(base + 17563648);           // 576 KB
  u16*   Vb   = (u16*)(base + 18153472);           // 576 KB
  u16*   sws  = (u16*)(base + 18743296);           // 18 MB

  hipMemcpyAsync(h, hs, 256 * 1024 * sizeof(float), hipMemcpyDeviceToDevice, stream);

  for (int l = 0; l < 8; ++l) {
    rmsnorm_k<<<256, 256, 0, stream>>>(h, x);
    // qkv: (256,1280,1024)
    gemm256<float, float, 0><<<dim3(40, 1, 1), 256, 0, stream>>>(
        x, qkvw + (long long)l * 1280 * 1024, qkv, 1024, 1024, 0, 0, 0, 1280, 1);
    transpose_past<<<dim3(32, 2, 2), 256, 0, stream>>>(
        pk + (long long)l * 2 * 64 * 2048, pv + (long long)l * 2 * 2048 * 64, Kb, Vb);
    rope_scatter<<<256, 256, 0, stream>>>(qkv, rc, rs, qb, Kb, Vb);
    // scores: per head (z=16): (256,2304,64), bf16 out
    gemm256<u16, u16, 1><<<dim3(72, 1, 16), 256, 0, stream>>>(
        qb, Kb, sws, 64, 64, 16384, 147456, 589824, 2304, 8);
    softmax_rows<<<4096, 256, 0, stream>>>(sws);
    hipMemsetAsync(oacc, 0, 256 * 1024 * sizeof(float), stream);
    // PV: per head: (256,64,2304), K-split 4, atomic into oacc (col offset 64*z)
    gemm256<u16, u16, 2><<<dim3(2, 4, 16), 256, 0, stream>>>(
        sws, Vb, oacc, 2304, 576, 589824, 147456, 64, 1024, 8);
    // o-proj: (256,1024,1024) K-split 4, atomic residual into h
    gemm256<float, float, 2><<<dim3(32, 4, 1), 256, 0, stream>>>(
        oacc, ow + (long long)l * 1024 * 1024, h, 1024, 256, 0, 0, 0, 1024, 1);
    rmsnorm_k<<<256, 256, 0, stream>>>(h, x);
    // gate_up: (256,8192,1024)
    gemm256<float, float, 0><<<dim3(256, 1, 1), 256, 0, stream>>>(
        x, guw + (long long)l * 8192 * 1024, gu, 1024, 1024, 0, 0, 0, 8192, 1);
    silu_mul<<<1024, 256, 0, stream>>>(gu, y);
    // down: (256,1024,4096) K-split 4, atomic residual into h
    gemm256<float, float, 2><<<dim3(32, 4, 1), 256, 0, stream>>>(
        y, dw + (long long)l * 1024 * 4096, h, 4096, 1024, 0, 0, 0, 1024, 1);
  }
  final_norm<<<256, 256, 0, stream>>>(h, nw, out);
}

// Round 2
// 1282.219 us; speedup vs baseline: 1.2900x; 1.2900x over previous
//
#include <hip/hip_runtime.h>
#include <hip/hip_bf16.h>

typedef __attribute__((ext_vector_type(4))) float f32x4;
typedef __attribute__((ext_vector_type(8))) __bf16 bf16x8;
typedef unsigned short u16;
typedef __attribute__((ext_vector_type(4))) unsigned short u16x4;
typedef __attribute__((ext_vector_type(8))) unsigned short u16x8;

__device__ __forceinline__ u16 f2bf(float f) {
  __bf16 h = (__bf16)f;
  return __builtin_bit_cast(u16, h);
}

__device__ __forceinline__ bf16x8 cvt8(const float* p) {
  f32x4 x = *(const f32x4*)p;
  f32x4 y = *(const f32x4*)(p + 4);
  bf16x8 r;
  r[0] = (__bf16)x[0]; r[1] = (__bf16)x[1]; r[2] = (__bf16)x[2]; r[3] = (__bf16)x[3];
  r[4] = (__bf16)y[0]; r[5] = (__bf16)y[1]; r[6] = (__bf16)y[2]; r[7] = (__bf16)y[3];
  return r;
}

// ---------------- weight GEMM: C[256 x N] (+)= A[256 x K]bf16 @ B[N x K]f32^T
// 512 threads = 8 waves; block tile 256M x 32N; wave w owns rows [w*32, w*32+32)
// grid.x = N/32, grid.y = K-splits. CMODE: 0 f32 store, 1 bf16 store, 2 f32 atomicAdd
template<int CMODE>
__global__ __launch_bounds__(512) void gemmW(
    const u16* __restrict__ A, const float* __restrict__ B,
    void* __restrict__ Cv, int K, int klen, int ldc)
{
  int n0 = blockIdx.x * 32;
  int kb = blockIdx.y * klen;
  int kend = kb + klen;
  int tid = threadIdx.x, lane = tid & 63, w = tid >> 6;
  int r0 = lane & 15, kof = (lane >> 4) << 3;

  const u16* a0 = A + (long long)(w * 32 + r0) * K + kof;
  const float* b0 = B + (long long)(n0 + r0) * K + kof;

  f32x4 acc[2][2];
#pragma unroll
  for (int i = 0; i < 2; i++)
#pragma unroll
    for (int j = 0; j < 2; j++) acc[i][j] = (f32x4){0.f, 0.f, 0.f, 0.f};

  bf16x8 af0 = *(const bf16x8*)(a0 + kb);
  bf16x8 af1 = *(const bf16x8*)(a0 + 16 * K + kb);
  bf16x8 bf0 = cvt8(b0 + kb);
  bf16x8 bf1 = cvt8(b0 + (long long)16 * K + kb);

  for (int k = kb + 32; k < kend; k += 32) {
    bf16x8 na0 = *(const bf16x8*)(a0 + k);
    bf16x8 na1 = *(const bf16x8*)(a0 + 16 * K + k);
    bf16x8 nb0 = cvt8(b0 + k);
    bf16x8 nb1 = cvt8(b0 + (long long)16 * K + k);
    acc[0][0] = __builtin_amdgcn_mfma_f32_16x16x32_bf16(af0, bf0, acc[0][0], 0, 0, 0);
    acc[0][1] = __builtin_amdgcn_mfma_f32_16x16x32_bf16(af0, bf1, acc[0][1], 0, 0, 0);
    acc[1][0] = __builtin_amdgcn_mfma_f32_16x16x32_bf16(af1, bf0, acc[1][0], 0, 0, 0);
    acc[1][1] = __builtin_amdgcn_mfma_f32_16x16x32_bf16(af1, bf1, acc[1][1], 0, 0, 0);
    af0 = na0; af1 = na1; bf0 = nb0; bf1 = nb1;
  }
  acc[0][0] = __builtin_amdgcn_mfma_f32_16x16x32_bf16(af0, bf0, acc[0][0], 0, 0, 0);
  acc[0][1] = __builtin_amdgcn_mfma_f32_16x16x32_bf16(af0, bf1, acc[0][1], 0, 0, 0);
  acc[1][0] = __builtin_amdgcn_mfma_f32_16x16x32_bf16(af1, bf0, acc[1][0], 0, 0, 0);
  acc[1][1] = __builtin_amdgcn_mfma_f32_16x16x32_bf16(af1, bf1, acc[1][1], 0, 0, 0);

  int rr = (lane >> 4) << 2;
#pragma unroll
  for (int mi = 0; mi < 2; mi++)
#pragma unroll
    for (int nj = 0; nj < 2; nj++)
#pragma unroll
      for (int q = 0; q < 4; q++) {
        int row = w * 32 + mi * 16 + rr + q;
        long long idx = (long long)row * ldc + n0 + nj * 16 + r0;
        float v = acc[mi][nj][q];
        if (CMODE == 0)      ((float*)Cv)[idx] = v;
        else if (CMODE == 1) ((u16*)Cv)[idx] = f2bf(v);
        else                 atomicAdd(((float*)Cv) + idx, v);
      }
}

// ---------------- rmsnorm (sum variant): x = bf16( h * rsqrt(sum h^2) )
__global__ __launch_bounds__(256) void rmsnorm_k(const float* __restrict__ h, u16* __restrict__ x) {
  int s = blockIdx.x, tid = threadIdx.x;
  __shared__ float red[4];
  f32x4 hv = ((const f32x4*)(h + s * 1024))[tid];
  float ss = hv[0]*hv[0] + hv[1]*hv[1] + hv[2]*hv[2] + hv[3]*hv[3];
#pragma unroll
  for (int off = 32; off > 0; off >>= 1) ss += __shfl_xor(ss, off, 64);
  int lane = tid & 63, w = tid >> 6;
  if (lane == 0) red[w] = ss;
  __syncthreads();
  ss = red[0] + red[1] + red[2] + red[3];
  float r = 1.0f / sqrtf(ss);
  u16x4 o;
#pragma unroll
  for (int c = 0; c < 4; c++) o[c] = f2bf(hv[c] * r);
  ((u16x4*)x)[s * 256 + tid] = o;
}

// ---------------- final norm
__global__ __launch_bounds__(256) void final_norm(const float* __restrict__ h,
                                                  const float* __restrict__ nw,
                                                  float* __restrict__ out) {
  int s = blockIdx.x, tid = threadIdx.x;
  __shared__ float red[4];
  f32x4 hv = ((const f32x4*)(h + s * 1024))[tid];
  float ss = hv[0]*hv[0] + hv[1]*hv[1] + hv[2]*hv[2] + hv[3]*hv[3];
#pragma unroll
  for (int off = 32; off > 0; off >>= 1) ss += __shfl_xor(ss, off, 64);
  int lane = tid & 63, w = tid >> 6;
  if (lane == 0) red[w] = ss;
  __syncthreads();
  ss = red[0] + red[1] + red[2] + red[3];
  float r = 1.0f / sqrtf(ss * (1.0f / 1024.0f) + 1e-6f);
  f32x4 wv = ((const f32x4*)nw)[tid];
  f32x4 o; o[0]=hv[0]*r*wv[0]; o[1]=hv[1]*r*wv[1]; o[2]=hv[2]*r*wv[2]; o[3]=hv[3]*r*wv[3];
  ((f32x4*)(out + s * 1024))[tid] = o;
}

// ---------------- transpose ALL layers' past K/V to bf16 MFMA layouts (once)
// Kb[l][kvh][t][d], Vb[l][kvh][d][t]; grid (32 t-tiles, 2 kvh, 16 = l*2+part)
__global__ __launch_bounds__(256) void transpose_past(const float* __restrict__ pk,
                                                      const float* __restrict__ pv,
                                                      u16* __restrict__ Kb, u16* __restrict__ Vb) {
  __shared__ float tile[64][65];
  int t0 = blockIdx.x * 64;
  int kvh = blockIdx.y;
  int l = blockIdx.z >> 1, part = blockIdx.z & 1;
  int lk = l * 2 + kvh;
  int tid = threadIdx.x;
  if (part == 0) {
    const float* src = pk + (long long)lk * 64 * 2048;        // [d][t]
#pragma unroll
    for (int r = 0; r < 16; r++) {
      int idx = r * 256 + tid; int d = idx >> 6, t = idx & 63;
      tile[d][t] = src[d * 2048 + t0 + t];
    }
    __syncthreads();
    u16* dst = Kb + (long long)lk * 2304 * 64;                // [t][d]
#pragma unroll
    for (int r = 0; r < 16; r++) {
      int idx = r * 256 + tid; int t = idx >> 6, d = idx & 63;
      dst[(t0 + t) * 64 + d] = f2bf(tile[d][t]);
    }
  } else {
    const float* src = pv + (long long)lk * 2048 * 64;        // [t][d]
#pragma unroll
    for (int r = 0; r < 16; r++) {
      int idx = r * 256 + tid; int t = idx >> 6, d = idx & 63;
      tile[t][d] = src[(t0 + t) * 64 + d];
    }
    __syncthreads();
    u16* dst = Vb + (long long)lk * 64 * 2304;                // [d][t]
#pragma unroll
    for (int r = 0; r < 16; r++) {
      int idx = r * 256 + tid; int d = idx >> 6, t = idx & 63;
      dst[d * 2304 + t0 + t] = f2bf(tile[t][d]);
    }
  }
}

// ---------------- rope + scatter new q/k/v (layer-sliced Kb/Vb pointers)
__global__ __launch_bounds__(256) void rope_scatter(const float* __restrict__ qkv,
                                                    const float* __restrict__ cs,
                                                    const float* __restrict__ sn,
                                                    u16* __restrict__ qb,
                                                    u16* __restrict__ Kb,
                                                    u16* __restrict__ Vb) {
  int s = blockIdx.x, tid = threadIdx.x;
  const float* row = qkv + s * 1280;
  for (int i = tid; i < 1280; i += 256) {
    int hh = i >> 6, d = i & 63;
    float v = row[i];
    if (hh < 18) {
      float vr = row[(hh << 6) | ((d + 32) & 63)];
      v = v * cs[s * 64 + d] + vr * sn[s * 64 + d];
      if (hh < 16) qb[hh * (256 * 64) + s * 64 + d] = f2bf(v);
      else         Kb[(hh - 16) * (2304 * 64) + (2048 + s) * 64 + d] = f2bf(v);
    } else {
      Vb[(hh - 18) * (64 * 2304) + d * 2304 + 2048 + s] = f2bf(v);
    }
  }
}

// ---------------- flash attention: grid (8 q-tiles of 32, 16 heads), 256 thr
// wave w handles T-range [w*576,(w+1)*576); partials combined in LDS.
__global__ __launch_bounds__(256) void flash_attn(
    const u16* __restrict__ qb, const u16* __restrict__ Kb2,
    const u16* __restrict__ Vb2, u16* __restrict__ oacc)
{
  __shared__ u16 Plds[4][32][40];
  __shared__ float Osh[4][32][68];
  __shared__ float msh[4][32];
  __shared__ float lsh[4][32];

  int hh = blockIdx.y, kvh = hh >> 3;
  int s0 = blockIdx.x * 32;
  int tid = threadIdx.x, lane = tid & 63, w = tid >> 6;
  int g = lane >> 4, r0 = lane & 15;

  const u16* Q  = qb  + hh * (256 * 64);
  const u16* Kh = Kb2 + kvh * (2304 * 64);
  const u16* Vh = Vb2 + kvh * (64 * 2304);

  bf16x8 qf[2][2];
#pragma unroll
  for (int mi = 0; mi < 2; mi++)
#pragma unroll
    for (int kk = 0; kk < 2; kk++)
      qf[mi][kk] = *(const bf16x8*)(Q + (s0 + mi * 16 + r0) * 64 + kk * 32 + g * 8);

  f32x4 O[2][4];
  f32x4 m[2], l[2];
#pragma unroll
  for (int mi = 0; mi < 2; mi++) {
#pragma unroll
    for (int dj = 0; dj < 4; dj++) O[mi][dj] = (f32x4){0.f, 0.f, 0.f, 0.f};
    m[mi] = (f32x4){-1e30f, -1e30f, -1e30f, -1e30f};
    l[mi] = (f32x4){0.f, 0.f, 0.f, 0.f};
  }

  int t0s = w * 576;
  for (int t0 = t0s; t0 < t0s + 576; t0 += 32) {
    bf16x8 kf[2][2];
#pragma unroll
    for (int tj = 0; tj < 2; tj++)
#pragma unroll
      for (int kk = 0; kk < 2; kk++)
        kf[tj][kk] = *(const bf16x8*)(Kh + (t0 + tj * 16 + r0) * 64 + kk * 32 + g * 8);

    f32x4 sc[2][2];
#pragma unroll
    for (int mi = 0; mi < 2; mi++)
#pragma unroll
      for (int tj = 0; tj < 2; tj++) {
        f32x4 z = (f32x4){0.f, 0.f, 0.f, 0.f};
        z = __builtin_amdgcn_mfma_f32_16x16x32_bf16(qf[mi][0], kf[tj][0], z, 0, 0, 0);
        z = __builtin_amdgcn_mfma_f32_16x16x32_bf16(qf[mi][1], kf[tj][1], z, 0, 0, 0);
        sc[mi][tj] = z;
      }

    if (t0 > 2017 + s0) {            // causal mask region: invalid when t > 2048+s
#pragma unroll
      for (int mi = 0; mi < 2; mi++)
#pragma unroll
        for (int tj = 0; tj < 2; tj++)
#pragma unroll
          for (int q = 0; q < 4; q++) {
            int tg = t0 + tj * 16 + r0;
            int sg = s0 + mi * 16 + g * 4 + q;
            if (tg > 2048 + sg) sc[mi][tj][q] = -1e30f;
          }
    }

#pragma unroll
    for (int mi = 0; mi < 2; mi++) {
      f32x4 rm;
#pragma unroll
      for (int q = 0; q < 4; q++) rm[q] = fmaxf(sc[mi][0][q], sc[mi][1][q]);
#pragma unroll
      for (int off = 1; off < 16; off <<= 1)
#pragma unroll
        for (int q = 0; q < 4; q++) rm[q] = fmaxf(rm[q], __shfl_xor(rm[q], off, 64));
      f32x4 mn, sca, rs;
#pragma unroll
      for (int q = 0; q < 4; q++) {
        mn[q] = fmaxf(m[mi][q], rm[q]);
        sca[q] = __expf(m[mi][q] - mn[q]);
        sc[mi][0][q] = __expf(sc[mi][0][q] - mn[q]);
        sc[mi][1][q] = __expf(sc[mi][1][q] - mn[q]);
        rs[q] = sc[mi][0][q] + sc[mi][1][q];
      }
#pragma unroll
      for (int off = 1; off < 16; off <<= 1)
#pragma unroll
        for (int q = 0; q < 4; q++) rs[q] += __shfl_xor(rs[q], off, 64);
#pragma unroll
      for (int q = 0; q < 4; q++) {
        l[mi][q] = l[mi][q] * sca[q] + rs[q];
        m[mi][q] = mn[q];
      }
#pragma unroll
      for (int dj = 0; dj < 4; dj++)
#pragma unroll
        for (int q = 0; q < 4; q++) O[mi][dj][q] *= sca[q];
#pragma unroll
      for (int tj = 0; tj < 2; tj++)
#pragma unroll
        for (int q = 0; q < 4; q++)
          Plds[w][mi * 16 + g * 4 + q][tj * 16 + r0] = f2bf(sc[mi][tj][q]);
    }

    bf16x8 pa[2];
#pragma unroll
    for (int mi = 0; mi < 2; mi++)
      pa[mi] = *(const bf16x8*)&Plds[w][mi * 16 + r0][g * 8];
    bf16x8 vf[4];
#pragma unroll
    for (int dj = 0; dj < 4; dj++)
      vf[dj] = *(const bf16x8*)(Vh + (dj * 16 + r0) * 2304 + t0 + g * 8);
#pragma unroll
    for (int mi = 0; mi < 2; mi++)
#pragma unroll
      for (int dj = 0; dj < 4; dj++)
        O[mi][dj] = __builtin_amdgcn_mfma_f32_16x16x32_bf16(pa[mi], vf[dj], O[mi][dj], 0, 0, 0);
  }

  // write partials
#pragma unroll
  for (int mi = 0; mi < 2; mi++)
#pragma unroll
    for (int dj = 0; dj < 4; dj++)
#pragma unroll
      for (int q = 0; q < 4; q++)
        Osh[w][mi * 16 + g * 4 + q][dj * 16 + r0] = O[mi][dj][q];
  if (r0 == 0) {
#pragma unroll
    for (int mi = 0; mi < 2; mi++)
#pragma unroll
      for (int q = 0; q < 4; q++) {
        msh[w][mi * 16 + g * 4 + q] = m[mi][q];
        lsh[w][mi * 16 + g * 4 + q] = l[mi][q];
      }
  }
  __syncthreads();

  // combine 4 wave-partials
  int row = tid >> 3, c0 = (tid & 7) * 8;
  float M = fmaxf(fmaxf(msh[0][row], msh[1][row]), fmaxf(msh[2][row], msh[3][row]));
  float L = 0.f;
  float accv[8];
#pragma unroll
  for (int c = 0; c < 8; c++) accv[c] = 0.f;
#pragma unroll
  for (int w4 = 0; w4 < 4; w4++) {
    float e = __expf(msh[w4][row] - M);
    L += lsh[w4][row] * e;
#pragma unroll
    for (int c = 0; c < 8; c++) accv[c] += e * Osh[w4][row][c0 + c];
  }
  float inv = 1.0f / L;
  u16x8 o8;
#pragma unroll
  for (int c = 0; c < 8; c++) o8[c] = f2bf(accv[c] * inv);
  *(u16x8*)(oacc + (long long)(s0 + row) * 1024 + hh * 64 + c0) = o8;
}

// ---------------- silu(gate)*up, bf16 in/out
__global__ __launch_bounds__(256) void silu_mul(const u16* __restrict__ gu, u16* __restrict__ y) {
  int t = blockIdx.x * 256 + threadIdx.x;     // 131072 threads, 8 elems each
  int s = t >> 9, i8 = (t & 511) * 8;
  bf16x8 gv = *(const bf16x8*)(gu + s * 8192 + i8);
  bf16x8 uv = *(const bf16x8*)(gu + s * 8192 + 4096 + i8);
  u16x8 o8;
#pragma unroll
  for (int c = 0; c < 8; c++) {
    float gg = (float)gv[c];
    float uu = (float)uv[c];
    o8[c] = f2bf((gg / (1.0f + __expf(-gg))) * uu);
  }
  *(u16x8*)(y + s * 4096 + i8) = o8;
}

// ---------------- launch ----------------
extern "C" void kernel_launch(void* const* d_in, const int* in_sizes, int n_in,
                              void* d_out, int out_size, void* d_ws, size_t ws_size,
                              hipStream_t stream) {
  (void)in_sizes; (void)n_in; (void)out_size; (void)ws_size;
  const float* hs   = (const float*)d_in[0];
  const float* rc   = (const float*)d_in[1];
  const float* rs   = (const float*)d_in[2];
  const float* pk   = (const float*)d_in[4];
  const float* pv   = (const float*)d_in[5];
  const float* qkvw = (const float*)d_in[6];
  const float* ow   = (const float*)d_in[7];
  const float* guw  = (const float*)d_in[8];
  const float* dw   = (const float*)d_in[9];
  const float* nw   = (const float*)d_in[10];
  float* out = (float*)d_out;

  char* base = (char*)d_ws;
  float* h   = (float*)(base + 0);           // 1 MB
  u16*  x    = (u16*)(base + 1048576);       // 0.5 MB
  float* qkv = (float*)(base + 1572864);     // 1.25 MB
  u16*  gu   = (u16*)(base + 2883584);       // 4 MB
  u16*  y    = (u16*)(base + 7077888);       // 2 MB
  u16*  oacc = (u16*)(base + 9175040);       // 0.5 MB
  u16*  qb   = (u16*)(base + 9699328);       // 0.5 MB
  u16*  Kb   = (u16*)(base + 10223616);      // 4.5 MB  [8][2][2304][64]
  u16*  Vb   = (u16*)(base + 14942208);      // 4.5 MB  [8][2][64][2304]

  hipMemcpyAsync(h, hs, 1048576, hipMemcpyDeviceToDevice, stream);
  transpose_past<<<dim3(32, 2, 16), 256, 0, stream>>>(pk, pv, Kb, Vb);

  for (int l = 0; l < 8; ++l) {
    u16* Kbl = Kb + (long long)l * 2 * 2304 * 64;
    u16* Vbl = Vb + (long long)l * 2 * 64 * 2304;

    rmsnorm_k<<<256, 256, 0, stream>>>(h, x);
    hipMemsetAsync(qkv, 0, 1310720, stream);
    gemmW<2><<<dim3(40, 2), 512, 0, stream>>>(
        x, qkvw + (long long)l * 1310720, qkv, 1024, 512, 1280);
    rope_scatter<<<256, 256, 0, stream>>>(qkv, rc, rs, qb, Kbl, Vbl);
    flash_attn<<<dim3(8, 16), 256, 0, stream>>>(qb, Kbl, Vbl, oacc);
    gemmW<2><<<dim3(32, 8), 512, 0, stream>>>(
        oacc, ow + (long long)l * 1048576, h, 1024, 128, 1024);
    rmsnorm_k<<<256, 256, 0, stream>>>(h, x);
    gemmW<1><<<dim3(256, 1), 512, 0, stream>>>(
        x, guw + (long long)l * 8388608, gu, 1024, 1024, 8192);
    silu_mul<<<512, 256, 0, stream>>>(gu, y);
    gemmW<2><<<dim3(32, 8), 512, 0, stream>>>(
        y, dw + (long long)l * 4194304, h, 4096, 512, 1024);
  }
  final_norm<<<256, 256, 0, stream>>>(h, nw, out);
}

// Round 3
// 1226.291 us; speedup vs baseline: 1.3488x; 1.0456x over previous
//
#include <hip/hip_runtime.h>
#include <hip/hip_bf16.h>

typedef __attribute__((ext_vector_type(4))) float f32x4;
typedef __attribute__((ext_vector_type(8))) __bf16 bf16x8;
typedef unsigned short u16;
typedef __attribute__((ext_vector_type(4))) unsigned short u16x4;
typedef __attribute__((ext_vector_type(8))) unsigned short u16x8;

__device__ __forceinline__ u16 f2bf(float f) {
  __bf16 h = (__bf16)f;
  return __builtin_bit_cast(u16, h);
}

__device__ __forceinline__ bf16x8 cvt2(f32x4 x, f32x4 y) {
  bf16x8 r;
  r[0] = (__bf16)x[0]; r[1] = (__bf16)x[1]; r[2] = (__bf16)x[2]; r[3] = (__bf16)x[3];
  r[4] = (__bf16)y[0]; r[5] = (__bf16)y[1]; r[6] = (__bf16)y[2]; r[7] = (__bf16)y[3];
  return r;
}

// ---------------- weight GEMM: C[256 x N] (+)= A[256 x K]bf16 @ B[N x K]f32^T
// 512 thr = 8 waves, wave tile 32M x 32N; 4-deep k-prefetch pipeline.
// grid.x = N/32, grid.y = ksplits (klen each, multiple of 128).
// CMODE: 0 f32 store, 1 bf16 store, 2 f32 atomicAdd
#define GW_LOAD(p, koff) { \
  pa[p][0] = *(const bf16x8*)(a0 + (koff)); \
  pa[p][1] = *(const bf16x8*)(a1 + (koff)); \
  pb[p][0][0] = *(const f32x4*)(b0 + (koff)); \
  pb[p][0][1] = *(const f32x4*)(b0 + (koff) + 4); \
  pb[p][1][0] = *(const f32x4*)(b1 + (koff)); \
  pb[p][1][1] = *(const f32x4*)(b1 + (koff) + 4); }

#define GW_COMP(p) { \
  bf16x8 bq0 = cvt2(pb[p][0][0], pb[p][0][1]); \
  bf16x8 bq1 = cvt2(pb[p][1][0], pb[p][1][1]); \
  acc[0][0] = __builtin_amdgcn_mfma_f32_16x16x32_bf16(pa[p][0], bq0, acc[0][0], 0, 0, 0); \
  acc[0][1] = __builtin_amdgcn_mfma_f32_16x16x32_bf16(pa[p][0], bq1, acc[0][1], 0, 0, 0); \
  acc[1][0] = __builtin_amdgcn_mfma_f32_16x16x32_bf16(pa[p][1], bq0, acc[1][0], 0, 0, 0); \
  acc[1][1] = __builtin_amdgcn_mfma_f32_16x16x32_bf16(pa[p][1], bq1, acc[1][1], 0, 0, 0); }

template<int CMODE>
__global__ __launch_bounds__(512) void gemmW(
    const u16* __restrict__ A, const float* __restrict__ B,
    void* __restrict__ Cv, int K, int klen, int ldc)
{
  int n0 = blockIdx.x * 32;
  int kb = blockIdx.y * klen;
  int tid = threadIdx.x, lane = tid & 63, w = tid >> 6;
  int r0 = lane & 15, kof = (lane >> 4) << 3;

  const u16* a0 = A + (long long)(w * 32 + r0) * K + kof + kb;
  const u16* a1 = a0 + (long long)16 * K;
  const float* b0 = B + (long long)(n0 + r0) * K + kof + kb;
  const float* b1 = b0 + (long long)16 * K;

  f32x4 acc[2][2];
#pragma unroll
  for (int i = 0; i < 2; i++)
#pragma unroll
    for (int j = 0; j < 2; j++) acc[i][j] = (f32x4){0.f, 0.f, 0.f, 0.f};

  bf16x8 pa[4][2];
  f32x4 pb[4][2][2];
  GW_LOAD(0, 0) GW_LOAD(1, 32) GW_LOAD(2, 64) GW_LOAD(3, 96)

  int nch = klen >> 7;
  for (int c = 0; c < nch - 1; c++) {
    int kn = (c + 1) << 7;
    GW_COMP(0) GW_LOAD(0, kn)
    GW_COMP(1) GW_LOAD(1, kn + 32)
    GW_COMP(2) GW_LOAD(2, kn + 64)
    GW_COMP(3) GW_LOAD(3, kn + 96)
  }
  GW_COMP(0) GW_COMP(1) GW_COMP(2) GW_COMP(3)

  int rr = (lane >> 4) << 2;
#pragma unroll
  for (int mi = 0; mi < 2; mi++)
#pragma unroll
    for (int nj = 0; nj < 2; nj++)
#pragma unroll
      for (int q = 0; q < 4; q++) {
        int row = w * 32 + mi * 16 + rr + q;
        long long idx = (long long)row * ldc + n0 + nj * 16 + r0;
        float v = acc[mi][nj][q];
        if (CMODE == 0)      ((float*)Cv)[idx] = v;
        else if (CMODE == 1) ((u16*)Cv)[idx] = f2bf(v);
        else                 atomicAdd(((float*)Cv) + idx, v);
      }
}

// ---------------- rmsnorm (sum variant): x = bf16( h * rsqrt(sum h^2) )
__global__ __launch_bounds__(256) void rmsnorm_k(const float* __restrict__ h, u16* __restrict__ x) {
  int s = blockIdx.x, tid = threadIdx.x;
  __shared__ float red[4];
  f32x4 hv = ((const f32x4*)(h + s * 1024))[tid];
  float ss = hv[0]*hv[0] + hv[1]*hv[1] + hv[2]*hv[2] + hv[3]*hv[3];
#pragma unroll
  for (int off = 32; off > 0; off >>= 1) ss += __shfl_xor(ss, off, 64);
  int lane = tid & 63, w = tid >> 6;
  if (lane == 0) red[w] = ss;
  __syncthreads();
  ss = red[0] + red[1] + red[2] + red[3];
  float r = 1.0f / sqrtf(ss);
  u16x4 o;
#pragma unroll
  for (int c = 0; c < 4; c++) o[c] = f2bf(hv[c] * r);
  ((u16x4*)x)[s * 256 + tid] = o;
}

// ---------------- final norm
__global__ __launch_bounds__(256) void final_norm(const float* __restrict__ h,
                                                  const float* __restrict__ nw,
                                                  float* __restrict__ out) {
  int s = blockIdx.x, tid = threadIdx.x;
  __shared__ float red[4];
  f32x4 hv = ((const f32x4*)(h + s * 1024))[tid];
  float ss = hv[0]*hv[0] + hv[1]*hv[1] + hv[2]*hv[2] + hv[3]*hv[3];
#pragma unroll
  for (int off = 32; off > 0; off >>= 1) ss += __shfl_xor(ss, off, 64);
  int lane = tid & 63, w = tid >> 6;
  if (lane == 0) red[w] = ss;
  __syncthreads();
  ss = red[0] + red[1] + red[2] + red[3];
  float r = 1.0f / sqrtf(ss * (1.0f / 1024.0f) + 1e-6f);
  f32x4 wv = ((const f32x4*)nw)[tid];
  f32x4 o; o[0]=hv[0]*r*wv[0]; o[1]=hv[1]*r*wv[1]; o[2]=hv[2]*r*wv[2]; o[3]=hv[3]*r*wv[3];
  ((f32x4*)(out + s * 1024))[tid] = o;
}

// ---------------- transpose ALL layers' past K/V to bf16 MFMA layouts (once)
__global__ __launch_bounds__(256) void transpose_past(const float* __restrict__ pk,
                                                      const float* __restrict__ pv,
                                                      u16* __restrict__ Kb, u16* __restrict__ Vb) {
  __shared__ float tile[64][65];
  int t0 = blockIdx.x * 64;
  int kvh = blockIdx.y;
  int l = blockIdx.z >> 1, part = blockIdx.z & 1;
  int lk = l * 2 + kvh;
  int tid = threadIdx.x;
  if (part == 0) {
    const float* src = pk + (long long)lk * 64 * 2048;        // [d][t]
#pragma unroll
    for (int r = 0; r < 16; r++) {
      int idx = r * 256 + tid; int d = idx >> 6, t = idx & 63;
      tile[d][t] = src[d * 2048 + t0 + t];
    }
    __syncthreads();
    u16* dst = Kb + (long long)lk * 2304 * 64;                // [t][d]
#pragma unroll
    for (int r = 0; r < 16; r++) {
      int idx = r * 256 + tid; int t = idx >> 6, d = idx & 63;
      dst[(t0 + t) * 64 + d] = f2bf(tile[d][t]);
    }
  } else {
    const float* src = pv + (long long)lk * 2048 * 64;        // [t][d]
#pragma unroll
    for (int r = 0; r < 16; r++) {
      int idx = r * 256 + tid; int t = idx >> 6, d = idx & 63;
      tile[t][d] = src[(t0 + t) * 64 + d];
    }
    __syncthreads();
    u16* dst = Vb + (long long)lk * 64 * 2304;                // [d][t]
#pragma unroll
    for (int r = 0; r < 16; r++) {
      int idx = r * 256 + tid; int d = idx >> 6, t = idx & 63;
      dst[d * 2304 + t0 + t] = f2bf(tile[t][d]);
    }
  }
}

// ---------------- rope + scatter new q/k/v
__global__ __launch_bounds__(256) void rope_scatter(const float* __restrict__ qkv,
                                                    const float* __restrict__ cs,
                                                    const float* __restrict__ sn,
                                                    u16* __restrict__ qb,
                                                    u16* __restrict__ Kb,
                                                    u16* __restrict__ Vb) {
  int s = blockIdx.x, tid = threadIdx.x;
  const float* row = qkv + s * 1280;
  for (int i = tid; i < 1280; i += 256) {
    int hh = i >> 6, d = i & 63;
    float v = row[i];
    if (hh < 18) {
      float vr = row[(hh << 6) | ((d + 32) & 63)];
      v = v * cs[s * 64 + d] + vr * sn[s * 64 + d];
      if (hh < 16) qb[hh * (256 * 64) + s * 64 + d] = f2bf(v);
      else         Kb[(hh - 16) * (2304 * 64) + (2048 + s) * 64 + d] = f2bf(v);
    } else {
      Vb[(hh - 18) * (64 * 2304) + d * 2304 + 2048 + s] = f2bf(v);
    }
  }
}

// ---------------- flash attention, swapped-operand form
// grid (16 q-tiles of 16, 16 heads), 256 thr = 4 waves; wave w owns T [w*576,(w+1)*576)
// scores C[t,s] = mfma(K,Q): s = lane&15 -> softmax reduce = in-reg + 2 shfl
// O[d,s] = mfma(V^T, P): per-lane scalar m/l/sca rescale.
struct KV { bf16x8 kf[2][2]; bf16x8 vf[4]; };

__global__ __launch_bounds__(256) void flash_attn(
    const u16* __restrict__ qb, const u16* __restrict__ Kb2,
    const u16* __restrict__ Vb2, u16* __restrict__ oacc)
{
  __shared__ u16 Plds[4][16][36];
  __shared__ float Osh[4][16][68];
  __shared__ float msh[4][16];
  __shared__ float lsh[4][16];

  int hh = blockIdx.y, kvh = hh >> 3;
  int s0 = blockIdx.x * 16;
  int tid = threadIdx.x, lane = tid & 63, w = tid >> 6;
  int g = lane >> 4, r0 = lane & 15;

  const u16* Q  = qb  + hh * (256 * 64);
  const u16* Kh = Kb2 + kvh * (2304 * 64);
  const u16* Vh = Vb2 + kvh * (64 * 2304);

  bf16x8 qf[2];
#pragma unroll
  for (int kk = 0; kk < 2; kk++)
    qf[kk] = *(const bf16x8*)(Q + (s0 + r0) * 64 + kk * 32 + g * 8);

  f32x4 O[4];
#pragma unroll
  for (int dj = 0; dj < 4; dj++) O[dj] = (f32x4){0.f, 0.f, 0.f, 0.f};
  float m = -1e30f, l = 0.f;

  int t0s = w * 576;

  auto loadkv = [&](KV& d, int t0) {
#pragma unroll
    for (int tj = 0; tj < 2; tj++)
#pragma unroll
      for (int kk = 0; kk < 2; kk++)
        d.kf[tj][kk] = *(const bf16x8*)(Kh + (t0 + tj * 16 + r0) * 64 + kk * 32 + g * 8);
#pragma unroll
    for (int dj = 0; dj < 4; dj++)
      d.vf[dj] = *(const bf16x8*)(Vh + (dj * 16 + r0) * 2304 + t0 + g * 8);
  };

  auto step = [&](KV& kv, int t0) {
    f32x4 sc[2];
#pragma unroll
    for (int tj = 0; tj < 2; tj++) {
      f32x4 z = (f32x4){0.f, 0.f, 0.f, 0.f};
      z = __builtin_amdgcn_mfma_f32_16x16x32_bf16(kv.kf[tj][0], qf[0], z, 0, 0, 0);
      z = __builtin_amdgcn_mfma_f32_16x16x32_bf16(kv.kf[tj][1], qf[1], z, 0, 0, 0);
      sc[tj] = z;
    }
    if (t0 + 31 > 2048 + s0) {               // causal mask: t > 2048 + s invalid
#pragma unroll
      for (int tj = 0; tj < 2; tj++)
#pragma unroll
        for (int q = 0; q < 4; q++) {
          int tg = t0 + tj * 16 + g * 4 + q;
          int sg = s0 + r0;
          if (tg > 2048 + sg) sc[tj][q] = -1e30f;
        }
    }
    float rm = -1e30f;
#pragma unroll
    for (int tj = 0; tj < 2; tj++)
#pragma unroll
      for (int q = 0; q < 4; q++) rm = fmaxf(rm, sc[tj][q]);
    rm = fmaxf(rm, __shfl_xor(rm, 16, 64));
    rm = fmaxf(rm, __shfl_xor(rm, 32, 64));
    float mn = fmaxf(m, rm);
    float sca = __expf(m - mn);
    float rs = 0.f;
#pragma unroll
    for (int tj = 0; tj < 2; tj++)
#pragma unroll
      for (int q = 0; q < 4; q++) {
        sc[tj][q] = __expf(sc[tj][q] - mn);
        rs += sc[tj][q];
      }
    rs += __shfl_xor(rs, 16, 64);
    rs += __shfl_xor(rs, 32, 64);
    l = l * sca + rs;
    m = mn;
#pragma unroll
    for (int dj = 0; dj < 4; dj++) {
      O[dj][0] *= sca; O[dj][1] *= sca; O[dj][2] *= sca; O[dj][3] *= sca;
    }
#pragma unroll
    for (int tj = 0; tj < 2; tj++) {
      u16x4 pw;
#pragma unroll
      for (int q = 0; q < 4; q++) pw[q] = f2bf(sc[tj][q]);
      *(u16x4*)&Plds[w][r0][tj * 16 + g * 4] = pw;
    }
    u16x4 plo = *(const u16x4*)&Plds[w][r0][g * 8];
    u16x4 phi = *(const u16x4*)&Plds[w][r0][g * 8 + 4];
    union { bf16x8 v; u16x4 h[2]; } pu;
    pu.h[0] = plo; pu.h[1] = phi;
#pragma unroll
    for (int dj = 0; dj < 4; dj++)
      O[dj] = __builtin_amdgcn_mfma_f32_16x16x32_bf16(kv.vf[dj], pu.v, O[dj], 0, 0, 0);
  };

  KV bufA, bufB;
  loadkv(bufA, t0s);
#pragma unroll 1
  for (int it = 0; it < 18; it += 2) {
    int t0 = t0s + it * 32;
    loadkv(bufB, t0 + 32);
    step(bufA, t0);
    if (it + 2 < 18) loadkv(bufA, t0 + 64);
    step(bufB, t0 + 32);
  }

  // write partials: O[dj] holds rows d = dj*16+g*4+q, col s = r0
#pragma unroll
  for (int dj = 0; dj < 4; dj++)
    *(f32x4*)&Osh[w][r0][dj * 16 + g * 4] = O[dj];
  if (g == 0) { msh[w][r0] = m; lsh[w][r0] = l; }
  __syncthreads();

  // combine: 16 rows (s) x 64 cols (d); thread -> row=tid>>4, 4 cols
  int row = tid >> 4, c0 = (tid & 15) * 4;
  float M = fmaxf(fmaxf(msh[0][row], msh[1][row]), fmaxf(msh[2][row], msh[3][row]));
  float L = 0.f;
  float a0 = 0.f, a1 = 0.f, a2 = 0.f, a3 = 0.f;
#pragma unroll
  for (int w4 = 0; w4 < 4; w4++) {
    float e = __expf(msh[w4][row] - M);
    L += lsh[w4][row] * e;
    f32x4 ov = *(const f32x4*)&Osh[w4][row][c0];
    a0 += e * ov[0]; a1 += e * ov[1]; a2 += e * ov[2]; a3 += e * ov[3];
  }
  float inv = 1.0f / L;
  u16x4 o4;
  o4[0] = f2bf(a0 * inv); o4[1] = f2bf(a1 * inv);
  o4[2] = f2bf(a2 * inv); o4[3] = f2bf(a3 * inv);
  *(u16x4*)(oacc + (long long)(s0 + row) * 1024 + hh * 64 + c0) = o4;
}

// ---------------- silu(gate)*up, bf16 in/out
__global__ __launch_bounds__(256) void silu_mul(const u16* __restrict__ gu, u16* __restrict__ y) {
  int t = blockIdx.x * 256 + threadIdx.x;
  int s = t >> 9, i8 = (t & 511) * 8;
  bf16x8 gv = *(const bf16x8*)(gu + s * 8192 + i8);
  bf16x8 uv = *(const bf16x8*)(gu + s * 8192 + 4096 + i8);
  u16x8 o8;
#pragma unroll
  for (int c = 0; c < 8; c++) {
    float gg = (float)gv[c];
    float uu = (float)uv[c];
    o8[c] = f2bf((gg / (1.0f + __expf(-gg))) * uu);
  }
  *(u16x8*)(y + s * 4096 + i8) = o8;
}

// ---------------- launch ----------------
extern "C" void kernel_launch(void* const* d_in, const int* in_sizes, int n_in,
                              void* d_out, int out_size, void* d_ws, size_t ws_size,
                              hipStream_t stream) {
  (void)in_sizes; (void)n_in; (void)out_size; (void)ws_size;
  const float* hs   = (const float*)d_in[0];
  const float* rc   = (const float*)d_in[1];
  const float* rs   = (const float*)d_in[2];
  const float* pk   = (const float*)d_in[4];
  const float* pv   = (const float*)d_in[5];
  const float* qkvw = (const float*)d_in[6];
  const float* ow   = (const float*)d_in[7];
  const float* guw  = (const float*)d_in[8];
  const float* dw   = (const float*)d_in[9];
  const float* nw   = (const float*)d_in[10];
  float* out = (float*)d_out;

  char* base = (char*)d_ws;
  float* h   = (float*)(base + 0);           // 1 MB
  u16*  x    = (u16*)(base + 1048576);       // 0.5 MB
  float* qkv = (float*)(base + 1572864);     // 1.25 MB
  u16*  gu   = (u16*)(base + 2883584);       // 4 MB
  u16*  y    = (u16*)(base + 7077888);       // 2 MB
  u16*  oacc = (u16*)(base + 9175040);       // 0.5 MB
  u16*  qb   = (u16*)(base + 9699328);       // 0.5 MB
  u16*  Kb   = (u16*)(base + 10223616);      // 4.5 MB  [8][2][2304][64]
  u16*  Vb   = (u16*)(base + 14942208);      // 4.5 MB  [8][2][64][2304]

  hipMemcpyAsync(h, hs, 1048576, hipMemcpyDeviceToDevice, stream);
  transpose_past<<<dim3(32, 2, 16), 256, 0, stream>>>(pk, pv, Kb, Vb);

  for (int l = 0; l < 8; ++l) {
    u16* Kbl = Kb + (long long)l * 2 * 2304 * 64;
    u16* Vbl = Vb + (long long)l * 2 * 64 * 2304;

    rmsnorm_k<<<256, 256, 0, stream>>>(h, x);
    hipMemsetAsync(qkv, 0, 1310720, stream);
    gemmW<2><<<dim3(40, 2), 512, 0, stream>>>(
        x, qkvw + (long long)l * 1310720, qkv, 1024, 512, 1280);
    rope_scatter<<<256, 256, 0, stream>>>(qkv, rc, rs, qb, Kbl, Vbl);
    flash_attn<<<dim3(16, 16), 256, 0, stream>>>(qb, Kbl, Vbl, oacc);
    gemmW<2><<<dim3(32, 2), 512, 0, stream>>>(
        oacc, ow + (long long)l * 1048576, h, 1024, 512, 1024);
    rmsnorm_k<<<256, 256, 0, stream>>>(h, x);
    gemmW<1><<<dim3(256, 1), 512, 0, stream>>>(
        x, guw + (long long)l * 8388608, gu, 1024, 1024, 8192);
    silu_mul<<<512, 256, 0, stream>>>(gu, y);
    gemmW<2><<<dim3(32, 8), 512, 0, stream>>>(
        y, dw + (long long)l * 4194304, h, 4096, 512, 1024);
  }
  final_norm<<<256, 256, 0, stream>>>(h, nw, out);
}

// Round 4
// 700.754 us; speedup vs baseline: 2.3604x; 1.7500x over previous
//
#include <hip/hip_runtime.h>
#include <hip/hip_bf16.h>

typedef __attribute__((ext_vector_type(4))) float f32x4;
typedef __attribute__((ext_vector_type(8))) __bf16 bf16x8;
typedef unsigned short u16;
typedef __attribute__((ext_vector_type(4))) unsigned short u16x4;
typedef __attribute__((ext_vector_type(8))) unsigned short u16x8;

__device__ __forceinline__ u16 f2bf(float f) {
  __bf16 h = (__bf16)f;
  return __builtin_bit_cast(u16, h);
}

__device__ __forceinline__ bf16x8 cvt2(f32x4 x, f32x4 y) {
  bf16x8 r;
  r[0] = (__bf16)x[0]; r[1] = (__bf16)x[1]; r[2] = (__bf16)x[2]; r[3] = (__bf16)x[3];
  r[4] = (__bf16)y[0]; r[5] = (__bf16)y[1]; r[6] = (__bf16)y[2]; r[7] = (__bf16)y[3];
  return r;
}

// ---------------- weight GEMM: C[256 x N] = A[256 x K]bf16 @ B[N x K]f32^T
// 512 thr = 8 waves partitioning M (wave w: rows w*32..w*32+32). BN=32, BK=128.
// B: fp32 global -> regs -> bf16 -> swizzled LDS (double-buffered), read once per byte.
// A: direct global bf16, ping-pong register prefetch.
// grid.x = N/32, grid.y = ksplit index (NBK*128 k each).
// CMODE: 0 = f32 store to partial slab (offset by blockIdx.y*256*ldc), 1 = bf16 store.
template<int CMODE, int NBK>
__global__ __launch_bounds__(512) void gemmW(
    const u16* __restrict__ A, const float* __restrict__ B,
    void* __restrict__ Cv, int K, int ldc)
{
  __shared__ char Bl[2][8192];           // 32 rows x 128 k x bf16, swizzled
  int n0 = blockIdx.x * 32;
  int kb = blockIdx.y * (NBK * 128);
  int tid = threadIdx.x, lane = tid & 63, w = tid >> 6;
  int r0 = lane & 15, g = lane >> 4;
  int trow = tid >> 4, tcol = tid & 15;  // staging: row 0..31, 16B-col 0..15

  const float* bsrc = B + (long long)(n0 + trow) * K + kb + tcol * 8;
  const u16* abase = A + (long long)(w * 32 + r0) * K + kb + g * 8;
  int swr = (trow & 7) << 4;
  int wofs = trow * 256 + ((tcol * 16) ^ swr);

  // stage BK 0
  {
    f32x4 u = *(const f32x4*)bsrc;
    f32x4 v = *(const f32x4*)(bsrc + 4);
    *(bf16x8*)&Bl[0][wofs] = cvt2(u, v);
  }
  bf16x8 a[2][2][4];                     // [pingpong][mi][kk]
#pragma unroll
  for (int mi = 0; mi < 2; mi++)
#pragma unroll
    for (int kk = 0; kk < 4; kk++)
      a[0][mi][kk] = *(const bf16x8*)(abase + (long long)mi * 16 * K + kk * 32);

  f32x4 acc[2][2];
#pragma unroll
  for (int i = 0; i < 2; i++)
#pragma unroll
    for (int j = 0; j < 2; j++) acc[i][j] = (f32x4){0.f, 0.f, 0.f, 0.f};

  __syncthreads();

#pragma unroll
  for (int ibk = 0; ibk < NBK; ibk++) {
    const int cur = ibk & 1;
    const int nxt = cur ^ 1;
    f32x4 u, v;
    if (ibk + 1 < NBK) {
      int ko = (ibk + 1) * 128;
#pragma unroll
      for (int mi = 0; mi < 2; mi++)
#pragma unroll
        for (int kk = 0; kk < 4; kk++)
          a[nxt][mi][kk] = *(const bf16x8*)(abase + (long long)mi * 16 * K + ko + kk * 32);
      u = *(const f32x4*)(bsrc + ko);
      v = *(const f32x4*)(bsrc + ko + 4);
    }
    // read B fragments from LDS (swizzled) + MFMA
    bf16x8 bfr[2][4];
#pragma unroll
    for (int nj = 0; nj < 2; nj++) {
      int row = nj * 16 + r0;
      int rb = row * 256, sw = (row & 7) << 4;
#pragma unroll
      for (int kk = 0; kk < 4; kk++)
        bfr[nj][kk] = *(const bf16x8*)&Bl[cur][rb + ((kk * 64 + g * 16) ^ sw)];
    }
#pragma unroll
    for (int kk = 0; kk < 4; kk++)
#pragma unroll
      for (int mi = 0; mi < 2; mi++)
#pragma unroll
        for (int nj = 0; nj < 2; nj++)
          acc[mi][nj] = __builtin_amdgcn_mfma_f32_16x16x32_bf16(a[cur][mi][kk], bfr[nj][kk], acc[mi][nj], 0, 0, 0);
    if (ibk + 1 < NBK)
      *(bf16x8*)&Bl[nxt][wofs] = cvt2(u, v);
    __syncthreads();
  }

  long long co = (long long)blockIdx.y * 256 * ldc;
  int rr = (lane >> 4) << 2;
#pragma unroll
  for (int mi = 0; mi < 2; mi++)
#pragma unroll
    for (int nj = 0; nj < 2; nj++)
#pragma unroll
      for (int q = 0; q < 4; q++) {
        int row = w * 32 + mi * 16 + rr + q;
        long long idx = co + (long long)row * ldc + n0 + nj * 16 + r0;
        float vv = acc[mi][nj][q];
        if (CMODE == 0) ((float*)Cv)[idx] = vv;
        else            ((u16*)Cv)[idx] = f2bf(vv);
      }
}

// ---------------- fused residual + rmsnorm (sum variant, no eps, no weight)
// h_new = src + sum(parts[0..np)); hout = h_new; x = bf16(h_new * rsqrt(sum h_new^2))
__global__ __launch_bounds__(256) void rms_fuse(const float* __restrict__ src,
                                                const float* __restrict__ parts, int np,
                                                float* __restrict__ hout, u16* __restrict__ x) {
  int s = blockIdx.x, tid = threadIdx.x;
  __shared__ float red[4];
  f32x4 hv = ((const f32x4*)(src + s * 1024))[tid];
  for (int p = 0; p < np; p++) {
    f32x4 pv = ((const f32x4*)(parts + (long long)p * 262144 + s * 1024))[tid];
    hv[0] += pv[0]; hv[1] += pv[1]; hv[2] += pv[2]; hv[3] += pv[3];
  }
  float ss = hv[0]*hv[0] + hv[1]*hv[1] + hv[2]*hv[2] + hv[3]*hv[3];
#pragma unroll
  for (int off = 32; off > 0; off >>= 1) ss += __shfl_xor(ss, off, 64);
  int lane = tid & 63, w = tid >> 6;
  if (lane == 0) red[w] = ss;
  __syncthreads();
  ss = red[0] + red[1] + red[2] + red[3];
  float r = 1.0f / sqrtf(ss);
  ((f32x4*)(hout + s * 1024))[tid] = hv;
  u16x4 o;
#pragma unroll
  for (int c = 0; c < 4; c++) o[c] = f2bf(hv[c] * r);
  ((u16x4*)x)[s * 256 + tid] = o;
}

// ---------------- final: h_new = h + sum(parts); out = h_new*rsqrt(mean+1e-6)*nw
__global__ __launch_bounds__(256) void final_fuse(const float* __restrict__ src,
                                                  const float* __restrict__ parts, int np,
                                                  const float* __restrict__ nw,
                                                  float* __restrict__ out) {
  int s = blockIdx.x, tid = threadIdx.x;
  __shared__ float red[4];
  f32x4 hv = ((const f32x4*)(src + s * 1024))[tid];
  for (int p = 0; p < np; p++) {
    f32x4 pv = ((const f32x4*)(parts + (long long)p * 262144 + s * 1024))[tid];
    hv[0] += pv[0]; hv[1] += pv[1]; hv[2] += pv[2]; hv[3] += pv[3];
  }
  float ss = hv[0]*hv[0] + hv[1]*hv[1] + hv[2]*hv[2] + hv[3]*hv[3];
#pragma unroll
  for (int off = 32; off > 0; off >>= 1) ss += __shfl_xor(ss, off, 64);
  int lane = tid & 63, w = tid >> 6;
  if (lane == 0) red[w] = ss;
  __syncthreads();
  ss = red[0] + red[1] + red[2] + red[3];
  float r = 1.0f / sqrtf(ss * (1.0f / 1024.0f) + 1e-6f);
  f32x4 wv = ((const f32x4*)nw)[tid];
  f32x4 o; o[0]=hv[0]*r*wv[0]; o[1]=hv[1]*r*wv[1]; o[2]=hv[2]*r*wv[2]; o[3]=hv[3]*r*wv[3];
  ((f32x4*)(out + s * 1024))[tid] = o;
}

// ---------------- transpose ALL layers' past K/V to bf16 MFMA layouts (once)
__global__ __launch_bounds__(256) void transpose_past(const float* __restrict__ pk,
                                                      const float* __restrict__ pv,
                                                      u16* __restrict__ Kb, u16* __restrict__ Vb) {
  __shared__ float tile[64][65];
  int t0 = blockIdx.x * 64;
  int kvh = blockIdx.y;
  int l = blockIdx.z >> 1, part = blockIdx.z & 1;
  int lk = l * 2 + kvh;
  int tid = threadIdx.x;
  if (part == 0) {
    const float* src = pk + (long long)lk * 64 * 2048;        // [d][t]
#pragma unroll
    for (int r = 0; r < 16; r++) {
      int idx = r * 256 + tid; int d = idx >> 6, t = idx & 63;
      tile[d][t] = src[d * 2048 + t0 + t];
    }
    __syncthreads();
    u16* dst = Kb + (long long)lk * 2304 * 64;                // [t][d]
#pragma unroll
    for (int r = 0; r < 16; r++) {
      int idx = r * 256 + tid; int t = idx >> 6, d = idx & 63;
      dst[(t0 + t) * 64 + d] = f2bf(tile[d][t]);
    }
  } else {
    const float* src = pv + (long long)lk * 2048 * 64;        // [t][d]
#pragma unroll
    for (int r = 0; r < 16; r++) {
      int idx = r * 256 + tid; int t = idx >> 6, d = idx & 63;
      tile[t][d] = src[(t0 + t) * 64 + d];
    }
    __syncthreads();
    u16* dst = Vb + (long long)lk * 64 * 2304;                // [d][t]
#pragma unroll
    for (int r = 0; r < 16; r++) {
      int idx = r * 256 + tid; int d = idx >> 6, t = idx & 63;
      dst[d * 2304 + t0 + t] = f2bf(tile[t][d]);
    }
  }
}

// ---------------- rope (sums 2 qkv partials) + scatter new q/k/v
__global__ __launch_bounds__(256) void rope_qkv(const float* __restrict__ P,
                                                const float* __restrict__ cs,
                                                const float* __restrict__ sn,
                                                u16* __restrict__ qb,
                                                u16* __restrict__ Kb,
                                                u16* __restrict__ Vb) {
  int s = blockIdx.x, tid = threadIdx.x;
  const float* p0 = P + (long long)s * 1280;
  const float* p1 = P + 327680 + (long long)s * 1280;
  for (int i = tid; i < 1280; i += 256) {
    int hh = i >> 6, d = i & 63;
    float v = p0[i] + p1[i];
    if (hh < 18) {
      int j = (hh << 6) | ((d + 32) & 63);
      float vr = p0[j] + p1[j];
      v = v * cs[s * 64 + d] + vr * sn[s * 64 + d];
      if (hh < 16) qb[hh * (256 * 64) + s * 64 + d] = f2bf(v);
      else         Kb[(hh - 16) * (2304 * 64) + (2048 + s) * 64 + d] = f2bf(v);
    } else {
      Vb[(hh - 18) * (64 * 2304) + d * 2304 + 2048 + s] = f2bf(v);
    }
  }
}

// ---------------- flash attention, swapped-operand form (unchanged, verified)
struct KV { bf16x8 kf[2][2]; bf16x8 vf[4]; };

__global__ __launch_bounds__(256) void flash_attn(
    const u16* __restrict__ qb, const u16* __restrict__ Kb2,
    const u16* __restrict__ Vb2, u16* __restrict__ oacc)
{
  __shared__ u16 Plds[4][16][36];
  __shared__ float Osh[4][16][68];
  __shared__ float msh[4][16];
  __shared__ float lsh[4][16];

  int hh = blockIdx.y, kvh = hh >> 3;
  int s0 = blockIdx.x * 16;
  int tid = threadIdx.x, lane = tid & 63, w = tid >> 6;
  int g = lane >> 4, r0 = lane & 15;

  const u16* Q  = qb  + hh * (256 * 64);
  const u16* Kh = Kb2 + kvh * (2304 * 64);
  const u16* Vh = Vb2 + kvh * (64 * 2304);

  bf16x8 qf[2];
#pragma unroll
  for (int kk = 0; kk < 2; kk++)
    qf[kk] = *(const bf16x8*)(Q + (s0 + r0) * 64 + kk * 32 + g * 8);

  f32x4 O[4];
#pragma unroll
  for (int dj = 0; dj < 4; dj++) O[dj] = (f32x4){0.f, 0.f, 0.f, 0.f};
  float m = -1e30f, l = 0.f;

  int t0s = w * 576;

  auto loadkv = [&](KV& d, int t0) {
#pragma unroll
    for (int tj = 0; tj < 2; tj++)
#pragma unroll
      for (int kk = 0; kk < 2; kk++)
        d.kf[tj][kk] = *(const bf16x8*)(Kh + (t0 + tj * 16 + r0) * 64 + kk * 32 + g * 8);
#pragma unroll
    for (int dj = 0; dj < 4; dj++)
      d.vf[dj] = *(const bf16x8*)(Vh + (dj * 16 + r0) * 2304 + t0 + g * 8);
  };

  auto step = [&](KV& kv, int t0) {
    f32x4 sc[2];
#pragma unroll
    for (int tj = 0; tj < 2; tj++) {
      f32x4 z = (f32x4){0.f, 0.f, 0.f, 0.f};
      z = __builtin_amdgcn_mfma_f32_16x16x32_bf16(kv.kf[tj][0], qf[0], z, 0, 0, 0);
      z = __builtin_amdgcn_mfma_f32_16x16x32_bf16(kv.kf[tj][1], qf[1], z, 0, 0, 0);
      sc[tj] = z;
    }
    if (t0 + 31 > 2048 + s0) {
#pragma unroll
      for (int tj = 0; tj < 2; tj++)
#pragma unroll
        for (int q = 0; q < 4; q++) {
          int tg = t0 + tj * 16 + g * 4 + q;
          int sg = s0 + r0;
          if (tg > 2048 + sg) sc[tj][q] = -1e30f;
        }
    }
    float rm = -1e30f;
#pragma unroll
    for (int tj = 0; tj < 2; tj++)
#pragma unroll
      for (int q = 0; q < 4; q++) rm = fmaxf(rm, sc[tj][q]);
    rm = fmaxf(rm, __shfl_xor(rm, 16, 64));
    rm = fmaxf(rm, __shfl_xor(rm, 32, 64));
    float mn = fmaxf(m, rm);
    float sca = __expf(m - mn);
    float rs = 0.f;
#pragma unroll
    for (int tj = 0; tj < 2; tj++)
#pragma unroll
      for (int q = 0; q < 4; q++) {
        sc[tj][q] = __expf(sc[tj][q] - mn);
        rs += sc[tj][q];
      }
    rs += __shfl_xor(rs, 16, 64);
    rs += __shfl_xor(rs, 32, 64);
    l = l * sca + rs;
    m = mn;
#pragma unroll
    for (int dj = 0; dj < 4; dj++) {
      O[dj][0] *= sca; O[dj][1] *= sca; O[dj][2] *= sca; O[dj][3] *= sca;
    }
#pragma unroll
    for (int tj = 0; tj < 2; tj++) {
      u16x4 pw;
#pragma unroll
      for (int q = 0; q < 4; q++) pw[q] = f2bf(sc[tj][q]);
      *(u16x4*)&Plds[w][r0][tj * 16 + g * 4] = pw;
    }
    u16x4 plo = *(const u16x4*)&Plds[w][r0][g * 8];
    u16x4 phi = *(const u16x4*)&Plds[w][r0][g * 8 + 4];
    union { bf16x8 v; u16x4 h[2]; } pu;
    pu.h[0] = plo; pu.h[1] = phi;
#pragma unroll
    for (int dj = 0; dj < 4; dj++)
      O[dj] = __builtin_amdgcn_mfma_f32_16x16x32_bf16(kv.vf[dj], pu.v, O[dj], 0, 0, 0);
  };

  KV bufA, bufB;
  loadkv(bufA, t0s);
#pragma unroll 1
  for (int it = 0; it < 18; it += 2) {
    int t0 = t0s + it * 32;
    loadkv(bufB, t0 + 32);
    step(bufA, t0);
    if (it + 2 < 18) loadkv(bufA, t0 + 64);
    step(bufB, t0 + 32);
  }

#pragma unroll
  for (int dj = 0; dj < 4; dj++)
    *(f32x4*)&Osh[w][r0][dj * 16 + g * 4] = O[dj];
  if (g == 0) { msh[w][r0] = m; lsh[w][r0] = l; }
  __syncthreads();

  int row = tid >> 4, c0 = (tid & 15) * 4;
  float M = fmaxf(fmaxf(msh[0][row], msh[1][row]), fmaxf(msh[2][row], msh[3][row]));
  float L = 0.f;
  float a0 = 0.f, a1 = 0.f, a2 = 0.f, a3 = 0.f;
#pragma unroll
  for (int w4 = 0; w4 < 4; w4++) {
    float e = __expf(msh[w4][row] - M);
    L += lsh[w4][row] * e;
    f32x4 ov = *(const f32x4*)&Osh[w4][row][c0];
    a0 += e * ov[0]; a1 += e * ov[1]; a2 += e * ov[2]; a3 += e * ov[3];
  }
  float inv = 1.0f / L;
  u16x4 o4;
  o4[0] = f2bf(a0 * inv); o4[1] = f2bf(a1 * inv);
  o4[2] = f2bf(a2 * inv); o4[3] = f2bf(a3 * inv);
  *(u16x4*)(oacc + (long long)(s0 + row) * 1024 + hh * 64 + c0) = o4;
}

// ---------------- silu(gate)*up, bf16 in/out
__global__ __launch_bounds__(256) void silu_mul(const u16* __restrict__ gu, u16* __restrict__ y) {
  int t = blockIdx.x * 256 + threadIdx.x;
  int s = t >> 9, i8 = (t & 511) * 8;
  bf16x8 gv = *(const bf16x8*)(gu + s * 8192 + i8);
  bf16x8 uv = *(const bf16x8*)(gu + s * 8192 + 4096 + i8);
  u16x8 o8;
#pragma unroll
  for (int c = 0; c < 8; c++) {
    float gg = (float)gv[c];
    float uu = (float)uv[c];
    o8[c] = f2bf((gg / (1.0f + __expf(-gg))) * uu);
  }
  *(u16x8*)(y + s * 4096 + i8) = o8;
}

// ---------------- launch ----------------
extern "C" void kernel_launch(void* const* d_in, const int* in_sizes, int n_in,
                              void* d_out, int out_size, void* d_ws, size_t ws_size,
                              hipStream_t stream) {
  (void)in_sizes; (void)n_in; (void)out_size; (void)ws_size;
  const float* hs   = (const float*)d_in[0];
  const float* rc   = (const float*)d_in[1];
  const float* rs   = (const float*)d_in[2];
  const float* pk   = (const float*)d_in[4];
  const float* pv   = (const float*)d_in[5];
  const float* qkvw = (const float*)d_in[6];
  const float* ow   = (const float*)d_in[7];
  const float* guw  = (const float*)d_in[8];
  const float* dw   = (const float*)d_in[9];
  const float* nw   = (const float*)d_in[10];
  float* out = (float*)d_out;

  char* base = (char*)d_ws;
  float* h   = (float*)(base + 0);            // 1 MB
  u16*  x    = (u16*)(base + 1048576);        // 0.5 MB
  float* Pq  = (float*)(base + 1572864);      // 2.5 MB  [2][256][1280]
  float* Po  = (float*)(base + 4194304);      // 4 MB    [4][256][1024]
  float* Pd  = (float*)(base + 8388608);      // 8 MB    [8][256][1024]
  u16*  gu   = (u16*)(base + 16777216);       // 4 MB
  u16*  y    = (u16*)(base + 20971520);       // 2 MB
  u16*  oacc = (u16*)(base + 23068672);       // 0.5 MB
  u16*  qb   = (u16*)(base + 23592960);       // 0.5 MB
  u16*  Kb   = (u16*)(base + 24117248);       // 4.5 MB  [8][2][2304][64]
  u16*  Vb   = (u16*)(base + 28835840);       // 4.5 MB  [8][2][64][2304]

  transpose_past<<<dim3(32, 2, 16), 256, 0, stream>>>(pk, pv, Kb, Vb);

  for (int l = 0; l < 8; ++l) {
    u16* Kbl = Kb + (long long)l * 2 * 2304 * 64;
    u16* Vbl = Vb + (long long)l * 2 * 64 * 2304;

    if (l == 0)
      rms_fuse<<<256, 256, 0, stream>>>(hs, nullptr, 0, h, x);
    else
      rms_fuse<<<256, 256, 0, stream>>>(h, Pd, 8, h, x);

    gemmW<0, 4><<<dim3(40, 2), 512, 0, stream>>>(
        x, qkvw + (long long)l * 1310720, Pq, 1024, 1280);
    rope_qkv<<<256, 256, 0, stream>>>(Pq, rc, rs, qb, Kbl, Vbl);
    flash_attn<<<dim3(16, 16), 256, 0, stream>>>(qb, Kbl, Vbl, oacc);
    gemmW<0, 2><<<dim3(32, 4), 512, 0, stream>>>(
        oacc, ow + (long long)l * 1048576, Po, 1024, 1024);
    rms_fuse<<<256, 256, 0, stream>>>(h, Po, 4, h, x);
    gemmW<1, 8><<<dim3(256, 1), 512, 0, stream>>>(
        x, guw + (long long)l * 8388608, gu, 1024, 8192);
    silu_mul<<<512, 256, 0, stream>>>(gu, y);
    gemmW<0, 4><<<dim3(32, 8), 512, 0, stream>>>(
        y, dw + (long long)l * 4194304, Pd, 4096, 1024);
  }
  final_fuse<<<256, 256, 0, stream>>>(h, Pd, 8, nw, out);
}